// Round 10
// baseline (176.336 us; speedup 1.0000x reference)
//
#include <hip/hip_runtime.h>
#include <hip/hip_bf16.h>
#include <cstdint>

// Net_79139067396690: MC-dropout moment-propagation MLP, fully fused.
//   h   = relu(0.5*x@W1^T + 0.5*sqrt((x^2)@(W1^2)^T) * eps1/sqrt(1000))
//   out =      0.5*h@W2^T + 0.5*sqrt((h^2)@(W2^2)^T) * eps2/sqrt(1000)
// Round 10: single fused kernel. BM=128 x BN=256 (full N) per block,
// 16 waves of 64x32 (per-wave mechanics identical to r9's verified kernel).
// h lives in LDS (never HBM); layer2 MFMA fused in-block (8 row-waves x
// 2 K-split waves + LDS partial reduction). L2 traffic halves (625 MB),
// x read once. Regs ~115 <= 128 tier -> 16 waves/CU kept.
// All register state NAMED (rule #20).

#define K_DIM 784
#define KP 800                 // K padded to multiple of 32 in the W1 pack
#define N_HID 256
#define N_OUT 10
#define BMF 128                // block rows
#define NSTEP 25               // KP/32
#define WSQ_OFF (N_HID * KP)   // u16 offset of squared-W1 pack
#define W2_OFF (832 * 1024)    // byte offset of W2 pack in d_ws
#define W2SQ 4096              // u16 offset of squared-W2 pack
#define HSTR 264               // hbuf row stride (u16), 16B-aligned

using short8 = __attribute__((ext_vector_type(8))) short;
using short4v = __attribute__((ext_vector_type(4))) short;
using floatx4 = __attribute__((ext_vector_type(4))) float;
typedef uint16_t u16;

// ---- Threefry-2x32 (JAX-compatible) ----
__host__ __device__ inline void threefry2x32(uint32_t k0, uint32_t k1,
                                             uint32_t x0, uint32_t x1,
                                             uint32_t& o0, uint32_t& o1) {
  uint32_t ks0 = k0, ks1 = k1, ks2 = k0 ^ k1 ^ 0x1BD11BDAu;
  x0 += ks0;
  x1 += ks1;
#define TFR(r) { x0 += x1; x1 = (x1 << (r)) | (x1 >> (32 - (r))); x1 ^= x0; }
  TFR(13) TFR(15) TFR(26) TFR(6)   x0 += ks1; x1 += ks2 + 1u;
  TFR(17) TFR(29) TFR(16) TFR(24)  x0 += ks2; x1 += ks0 + 2u;
  TFR(13) TFR(15) TFR(26) TFR(6)   x0 += ks0; x1 += ks1 + 3u;
  TFR(17) TFR(29) TFR(16) TFR(24)  x0 += ks1; x1 += ks2 + 4u;
  TFR(13) TFR(15) TFR(26) TFR(6)   x0 += ks2; x1 += ks0 + 5u;
#undef TFR
  o0 = x0;
  o1 = x1;
}

// bits -> N(0,1) ~= jax.random.normal (mantissa-uniform + Giles erfinv).
__device__ __forceinline__ float bits_to_normal(uint32_t bits) {
  const float lo = -0.99999994f;  // nextafterf(-1,0)
  float u01 = __uint_as_float((bits >> 9) | 0x3F800000u) - 1.0f;
  float u = fmaxf(lo, u01 * 2.0f + lo);
  float w = -__logf((1.0f - u) * (1.0f + u));
  float p;
  if (w < 5.0f) {
    w -= 2.5f;
    p = 2.81022636e-08f;
    p = fmaf(p, w, 3.43273939e-07f);
    p = fmaf(p, w, -3.5233877e-06f);
    p = fmaf(p, w, -4.39150654e-06f);
    p = fmaf(p, w, 0.00021858087f);
    p = fmaf(p, w, -0.00125372503f);
    p = fmaf(p, w, -0.00417768164f);
    p = fmaf(p, w, 0.246640727f);
    p = fmaf(p, w, 1.50140941f);
  } else {
    w = sqrtf(w) - 3.0f;
    p = -0.000200214257f;
    p = fmaf(p, w, 0.000100950558f);
    p = fmaf(p, w, 0.00134934322f);
    p = fmaf(p, w, -0.00367342844f);
    p = fmaf(p, w, 0.00573950773f);
    p = fmaf(p, w, -0.0076224613f);
    p = fmaf(p, w, 0.00943887047f);
    p = fmaf(p, w, 1.00167406f);
    p = fmaf(p, w, 2.83297682f);
  }
  return 1.41421356f * (p * u);
}

__device__ __forceinline__ float eps_part(uint32_t ka, uint32_t kb, uint32_t i) {
  uint32_t o0, o1;
  threefry2x32(ka, kb, 0u, i, o0, o1);
  return bits_to_normal(o0 ^ o1);
}

// f32 -> bf16 via hw cvt (RNE)
__device__ __forceinline__ u16 cvt_bf16(float f) {
  union { __hip_bfloat16 h; u16 u; } c;
  c.h = __float2bfloat16(f);
  return c.u;
}

__device__ __forceinline__ float bf2f(u16 b) {
  return __uint_as_float((uint32_t)b << 16);
}

// ---- pre-pack W1 -> bf16 {w, w^2}, K padded to 800 with zeros ----
__global__ __launch_bounds__(256) void pack_w1(const float* __restrict__ W1,
                                               u16* __restrict__ bp) {
  const int col = blockIdx.x;  // 0..255
  for (int k = threadIdx.x; k < KP; k += 256) {
    float w = (k < K_DIM) ? W1[col * K_DIM + k] : 0.0f;
    bp[col * KP + k] = cvt_bf16(w);
    bp[WSQ_OFF + col * KP + k] = cvt_bf16(w * w);
  }
}

// ---- pre-pack W2 -> bf16 {w, w^2}, cols padded 10->16 with zeros ----
__global__ __launch_bounds__(256) void pack_w2(const float* __restrict__ W2,
                                               u16* __restrict__ w2p) {
#pragma unroll
  for (int i = 0; i < 16; ++i) {
    int g = threadIdx.x + i * 256;  // 4096 = 16*256
    int col = g >> 8, k = g & 255;
    float w = (col < N_OUT) ? W2[col * N_HID + k] : 0.0f;
    w2p[g] = cvt_bf16(w);
    w2p[W2SQ + g] = cvt_bf16(w * w);
  }
}

// ---- fused kernel: 1024 thr = 16 waves; 128 rows x 256 cols; both layers ----
__global__ __launch_bounds__(1024, 4) void fused(
    const float* __restrict__ x, const u16* __restrict__ bp,
    const u16* __restrict__ w2p, float* __restrict__ out,
    uint32_t k1a, uint32_t k1b, uint32_t k2a, uint32_t k2b) {
  __shared__ u16 sA[2][2][BMF * 32];  // 32 KB  [dbuf][x, x^2][swizzled]
  __shared__ u16 hbuf[BMF * HSTR];    // 67.6 KB  h (bf16)

  const int tid = threadIdx.x;
  const int lane = tid & 63;
  const int l15 = lane & 15;
  const int lhal = lane >> 4;   // 0..3
  const int wid = tid >> 6;     // 0..15
  const int wm = wid >> 3;      // 0..1  (64-row half)
  const int wn = wid & 7;       // 0..7  (32-col strip)
  const int gr0 = blockIdx.x * BMF;

  // staging: thread -> (row 0..127, 4-wide k chunk)
  const int srow = tid >> 3;
  const int skq = (tid & 7) * 4;
  const float* xptr = x + (size_t)(gr0 + srow) * K_DIM + skq;
  const int sidx = (srow * 32 + skq) ^ ((srow & 7) << 3);  // u16 units

  // B offsets (u16) for this wave's two 16-col fragments
  const uint32_t boff0 = (uint32_t)(wn * 32 + l15) * KP + (uint32_t)lhal * 8;
  const uint32_t boff1 = boff0 + 16u * KP;

  // A fragment LDS indices (rows wm*64 + i*16 + l15), NAMED
#define AIDX(i) ((((wm * 64 + i * 16 + l15) * 32 + lhal * 8)) ^ ((l15 & 7) << 3))
  const int aidx0 = AIDX(0);
  const int aidx1 = AIDX(1);
  const int aidx2 = AIDX(2);
  const int aidx3 = AIDX(3);
#undef AIDX

  // NAMED accumulators
#define DECL_ACC(i) \
  floatx4 am##i##0 = {0.f, 0.f, 0.f, 0.f}, am##i##1 = {0.f, 0.f, 0.f, 0.f}; \
  floatx4 av##i##0 = {0.f, 0.f, 0.f, 0.f}, av##i##1 = {0.f, 0.f, 0.f, 0.f};
  DECL_ACC(0) DECL_ACC(1) DECL_ACC(2) DECL_ACC(3)
#undef DECL_ACC

  float4 q;
  auto loadX = [&](int kk) {
    if (kk + skq + 4 <= K_DIM) {  // zero-fill the 784..799 tail
      q = *reinterpret_cast<const float4*>(xptr + kk);
    } else {
      q = make_float4(0.f, 0.f, 0.f, 0.f);
    }
  };
  auto writeA = [&](int buf) {
    short4v va, v2;
    va[0] = (short)cvt_bf16(q.x); v2[0] = (short)cvt_bf16(q.x * q.x);
    va[1] = (short)cvt_bf16(q.y); v2[1] = (short)cvt_bf16(q.y * q.y);
    va[2] = (short)cvt_bf16(q.z); v2[2] = (short)cvt_bf16(q.z * q.z);
    va[3] = (short)cvt_bf16(q.w); v2[3] = (short)cvt_bf16(q.w * q.w);
    *reinterpret_cast<short4v*>(&sA[buf][0][sidx]) = va;
    *reinterpret_cast<short4v*>(&sA[buf][1][sidx]) = v2;
  };

  // prologue: stage step 0
  loadX(0);
  writeA(0);
  __syncthreads();

  for (int s = 0; s < NSTEP; ++s) {
    const int cur = s & 1, nxt = cur ^ 1;
    const bool have = (s + 1 < NSTEP);
    const int kk = s * 32;

    // B for this step, fresh from L2 (819 KB pack is L2-resident)
    const u16* bpk = bp + kk;
    const short8 bm0 = *reinterpret_cast<const short8*>(&bpk[boff0]);
    const short8 bm1 = *reinterpret_cast<const short8*>(&bpk[boff1]);
    const short8 bv0 = *reinterpret_cast<const short8*>(&bpk[WSQ_OFF + boff0]);
    const short8 bv1 = *reinterpret_cast<const short8*>(&bpk[WSQ_OFF + boff1]);

    if (have) loadX(kk + 32);  // x prefetch for next tile

    const u16* sc0 = &sA[cur][0][0];
    const u16* sc1 = &sA[cur][1][0];
#define STEP_I(i) { \
    const short8 af = *reinterpret_cast<const short8*>(&sc0[aidx##i]); \
    const short8 ag = *reinterpret_cast<const short8*>(&sc1[aidx##i]); \
    am##i##0 = __builtin_amdgcn_mfma_f32_16x16x32_bf16(af, bm0, am##i##0, 0, 0, 0); \
    av##i##0 = __builtin_amdgcn_mfma_f32_16x16x32_bf16(ag, bv0, av##i##0, 0, 0, 0); \
    am##i##1 = __builtin_amdgcn_mfma_f32_16x16x32_bf16(af, bm1, am##i##1, 0, 0, 0); \
    av##i##1 = __builtin_amdgcn_mfma_f32_16x16x32_bf16(ag, bv1, av##i##1, 0, 0, 0); }
    STEP_I(0) STEP_I(1) STEP_I(2) STEP_I(3)
#undef STEP_I

    if (have) writeA(nxt);
    __syncthreads();
  }

  // --- layer-1 epilogue: eps1 + relu -> hbuf (bf16 in LDS) ---
  const float INV = 0.031622776601683794f;  // 1/sqrt(1000)
#define EPIG(AM, AV, G, I, J) do { \
    const int rl_ = wm * 64 + I * 16 + lhal * 4 + (G); \
    const int c_ = wn * 32 + J * 16 + l15; \
    float mean_ = 0.5f * (AM)[G]; \
    float sd_ = 0.5f * sqrtf((AV)[G]); \
    uint32_t idx_ = (uint32_t)(gr0 + rl_) * 256u + (uint32_t)c_; \
    float eps_ = eps_part(k1a, k1b, idx_); \
    float h_ = fmaxf(mean_ + sd_ * (eps_ * INV), 0.0f); \
    hbuf[rl_ * HSTR + c_] = cvt_bf16(h_); \
  } while (0)
#define EPI(i, j) do { \
    EPIG(am##i##j, av##i##j, 0, i, j); \
    EPIG(am##i##j, av##i##j, 1, i, j); \
    EPIG(am##i##j, av##i##j, 2, i, j); \
    EPIG(am##i##j, av##i##j, 3, i, j); \
  } while (0)
  EPI(0, 0); EPI(0, 1); EPI(1, 0); EPI(1, 1);
  EPI(2, 0); EPI(2, 1); EPI(3, 0); EPI(3, 1);
#undef EPI
#undef EPIG
  __syncthreads();

  // --- layer 2 (fused, MFMA): wave wq owns rows wq*16..+15; kh = K half ---
  const int wq = wid & 7;
  const int kh = wid >> 3;          // 0: k 0..127, 1: k 128..255
  const int kbase = kh * 128;
  const int arow = wq * 16 + l15;
  const uint32_t b2off = (uint32_t)l15 * 256 + (uint32_t)lhal * 8;
  floatx4 am2 = {0.f, 0.f, 0.f, 0.f}, av2 = {0.f, 0.f, 0.f, 0.f};
#define SQ8(DST, SRC) do { \
    float f0_ = bf2f((u16)(SRC)[0]); (DST)[0] = (short)cvt_bf16(f0_ * f0_); \
    float f1_ = bf2f((u16)(SRC)[1]); (DST)[1] = (short)cvt_bf16(f1_ * f1_); \
    float f2_ = bf2f((u16)(SRC)[2]); (DST)[2] = (short)cvt_bf16(f2_ * f2_); \
    float f3_ = bf2f((u16)(SRC)[3]); (DST)[3] = (short)cvt_bf16(f3_ * f3_); \
    float f4_ = bf2f((u16)(SRC)[4]); (DST)[4] = (short)cvt_bf16(f4_ * f4_); \
    float f5_ = bf2f((u16)(SRC)[5]); (DST)[5] = (short)cvt_bf16(f5_ * f5_); \
    float f6_ = bf2f((u16)(SRC)[6]); (DST)[6] = (short)cvt_bf16(f6_ * f6_); \
    float f7_ = bf2f((u16)(SRC)[7]); (DST)[7] = (short)cvt_bf16(f7_ * f7_); \
  } while (0)
#define L2S(T) do { \
    const int k_ = kbase + (T) * 32; \
    const short8 af_ = *reinterpret_cast<const short8*>(&hbuf[arow * HSTR + k_ + lhal * 8]); \
    short8 ag_; \
    SQ8(ag_, af_); \
    const short8 bm_ = *reinterpret_cast<const short8*>(&w2p[b2off + k_]); \
    const short8 bv_ = *reinterpret_cast<const short8*>(&w2p[W2SQ + b2off + k_]); \
    am2 = __builtin_amdgcn_mfma_f32_16x16x32_bf16(af_, bm_, am2, 0, 0, 0); \
    av2 = __builtin_amdgcn_mfma_f32_16x16x32_bf16(ag_, bv_, av2, 0, 0, 0); \
  } while (0)
  L2S(0); L2S(1); L2S(2); L2S(3);
#undef L2S
#undef SQ8

  // partial reduction across the 2 K-halves via LDS (aliases sA, now dead)
  float* red = reinterpret_cast<float*>(&sA[0][0][0]);  // 16 KB used
  if (kh == 1) {
    const int rb = wq * 512 + lhal * 64 + l15;  // (lhal*4+g)*16 + l15, g via +16
    red[rb + 0] = am2[0];  red[rb + 16] = am2[1];
    red[rb + 32] = am2[2]; red[rb + 48] = am2[3];
    red[rb + 256 + 0] = av2[0];  red[rb + 256 + 16] = av2[1];
    red[rb + 256 + 32] = av2[2]; red[rb + 256 + 48] = av2[3];
  }
  __syncthreads();
  if (kh == 0) {
    const int rb = wq * 512 + lhal * 64 + l15;
    am2[0] += red[rb + 0];  am2[1] += red[rb + 16];
    am2[2] += red[rb + 32]; am2[3] += red[rb + 48];
    av2[0] += red[rb + 256 + 0];  av2[1] += red[rb + 256 + 16];
    av2[2] += red[rb + 256 + 32]; av2[3] += red[rb + 256 + 48];
    if (l15 < N_OUT) {
#define L2E(G) do { \
      const int row_ = gr0 + wq * 16 + lhal * 4 + (G); \
      float mean_ = 0.5f * am2[G]; \
      float sd_ = 0.5f * sqrtf(av2[G]); \
      float eps_ = eps_part(k2a, k2b, (uint32_t)row_ * 10u + (uint32_t)l15); \
      out[(size_t)row_ * 10 + l15] = mean_ + sd_ * (eps_ * INV); \
    } while (0)
      L2E(0); L2E(1); L2E(2); L2E(3);
#undef L2E
    }
  }
}

extern "C" void kernel_launch(void* const* d_in, const int* in_sizes, int n_in,
                              void* d_out, int out_size, void* d_ws, size_t ws_size,
                              hipStream_t stream) {
  const float* x = (const float*)d_in[0];
  const float* W1 = (const float*)d_in[1];
  const float* W2 = (const float*)d_in[2];
  float* outp = (float*)d_out;
  u16* bp = (u16*)d_ws;                           // 819200 B
  u16* w2p = (u16*)((char*)d_ws + W2_OFF);        // 16 KB

  // k1, k2 = jax.random.split(jax.random.key(42)), partitionable threefry
  uint32_t k1a, k1b, k2a, k2b;
  threefry2x32(0u, 42u, 0u, 0u, k1a, k1b);
  threefry2x32(0u, 42u, 0u, 1u, k2a, k2b);

  pack_w1<<<256, 256, 0, stream>>>(W1, bp);
  pack_w2<<<1, 256, 0, stream>>>(W2, w2p);
  fused<<<65536 / BMF, 1024, 0, stream>>>(x, bp, w2p, outp, k1a, k1b, k2a, k2b);
}